// Round 18
// baseline (38.388 us; speedup 1.0000x reference)
//
#include <hip/hip_runtime.h>

// Problem constants (match reference)
constexpr int B    = 64;
constexpr int E    = 512;
constexpr int P    = 31;    // patch size
constexpr int S    = 200;   // canvas size
constexpr int HALF = 15;

// Tiling: 16x16 canvas tiles
constexpr int TS     = 16;
constexpr int NTD    = (S + TS - 1) / TS;    // 13 tiles per dim
constexpr int NTILES = NTD * NTD;            // 169 tiles per batch
constexpr int NBINS  = B * NTILES;           // 10816
constexpr int CAP    = 128;                  // words per bin: 4 header + 124 entries
constexpr int ECAP   = CAP - 4;              // usable entries (mean ~25, tail ~60)

constexpr int THREADS = 256;
constexpr int NW      = THREADS / 64;        // 4 waves
constexpr int NXCD    = 8;

// ---- Binning (R16-verified core): one block per batch, LDS counters, no
// ---- global atomics, no memset. Count embedded as word 0 of the bin.
__global__ __launch_bounds__(E)
void imgs4dto3d_bin_kernel(const int* __restrict__ xyz,
                           unsigned*  __restrict__ entries)
{
    __shared__ int cnt[NTILES];

    const int b = blockIdx.x;
    const int e = threadIdx.x;                   // one thread per emitter

    for (int i = e; i < NTILES; i += E) cnt[i] = 0;
    __syncthreads();

    const int x = xyz[(size_t)(b * E + e) * 3 + 0];
    const int y = xyz[(size_t)(b * E + e) * 3 + 1];
    const unsigned pk = (unsigned)e | ((unsigned)x << 9) | ((unsigned)y << 17);

    const int tr_lo = (x - HALF) >> 4, tr_hi = (x + HALF) >> 4;
    const int tc_lo = (y - HALF) >> 4, tc_hi = (y + HALF) >> 4;

    for (int tr = tr_lo; tr <= tr_hi; ++tr) {
        for (int tc = tc_lo; tc <= tc_hi; ++tc) {
            const int t   = tr * NTD + tc;
            const int pos = atomicAdd(&cnt[t], 1);          // LDS atomic
            if (pos < ECAP)
                entries[(size_t)(b * NTILES + t) * CAP + 4 + pos] = pk;
        }
    }
    __syncthreads();

    for (int i = e; i < NTILES; i += E)
        entries[(size_t)(b * NTILES + i) * CAP] = (unsigned)cnt[i];  // header word 0
}

__global__ __launch_bounds__(THREADS)
void imgs4dto3d_gather_kernel(const float*    __restrict__ img,
                              const unsigned* __restrict__ entries,
                              float*          __restrict__ out)
{
    // XCD-locality swizzle (R15-verified): all 169 tiles of a batch on one XCD.
    const int wgid = blockIdx.x;
    const int xcd  = wgid & (NXCD - 1);
    const int seq  = wgid >> 3;
    const int b    = ((seq / NTILES) << 3) | xcd;
    const int t    = seq % NTILES;

    const int tid  = threadIdx.x;
    const int wid  = tid >> 6;
    const int lane = tid & 63;

    const int bin = b * NTILES + t;
    const uint4* lst4 = reinterpret_cast<const uint4*>(entries + (size_t)bin * CAP);

    // Static strided assignment: wave w owns entry-groups g == w (mod 4).
    // Entry j of group (w, k): j = 4*w + 16*k + u. Addresses independent of n,
    // so header + first two group words issue as ONE independent burst.
    const uint4 hdr = lst4[0];
    const uint4 g0  = lst4[1 + wid];          // k = 0
    const uint4 g1  = lst4[5 + wid];          // k = 1

    const int tr = t / NTD;
    const int tc = t % NTD;
    const int r0 = tr * TS;
    const int c0 = tc * TS;

    // lane map (R6/R12-verified): col = lane&15, rowg = lane>>4; 4 rows per lane
    const int col  = lane & 15;
    const int rowg = lane >> 4;
    const int c    = c0 + col;

    const int rr = r0 + rowg * 4 + HALF;    // pr0 = rr - x
    const int cc = c + HALF;                // pc  = cc - y

    const int n = min((int)hdr.x, ECAP);

    float a0 = 0.f, a1 = 0.f, a2 = 0.f, a3 = 0.f;
    const float* imgb = img + (size_t)b * E * (P * P);

    // process 8 entries (two groups) per burst: decode, issue 32 predicated
    // loads into staging regs, then accumulate (R17-verified inner body).
    auto process8 = [&](uint4 ga, uint4 gb, int jb0, int jb1) {
        const unsigned pks[8] = {ga.x, ga.y, ga.z, ga.w, gb.x, gb.y, gb.z, gb.w};
        float v[8][4];
        #pragma unroll
        for (int u = 0; u < 8; ++u) {
            const int j = ((u < 4) ? jb0 : jb1) + (u & 3);
            const bool inb = j < n;                          // wave-uniform
            const unsigned pk = pks[u];
            const int e = (int)(pk & 511u);
            const int x = (int)((pk >> 9) & 255u);
            const int y = (int)(pk >> 17);

            const int pc  = cc - y;                          // patch col (verified math)
            const int pr0 = rr - x;                          // patch row for q=0
            const bool colok = inb && ((unsigned)pc <= 30u);
            const float* bp = imgb + (size_t)e * (P * P) + pr0 * P + pc;
            #pragma unroll
            for (int q = 0; q < 4; ++q) {
                const bool kq = colok && ((unsigned)(pr0 + q) <= 30u);
                v[u][q] = kq ? bp[P * q] : 0.f;              // exec-masked load
            }
        }
        #pragma unroll
        for (int u = 0; u < 8; ++u) {
            a0 += v[u][0]; a1 += v[u][1]; a2 += v[u][2]; a3 += v[u][3];
        }
    };

    process8(g0, g1, 4 * wid, 4 * wid + 16);

    // rare tail: groups k >= 2 (only when n > 32)
    for (int k = 2; 4 * wid + 16 * k < n; k += 2) {
        const uint4 ga = lst4[1 + wid + 4 * k];
        const uint4 gb = lst4[min(1 + wid + 4 * (k + 1), CAP / 4 - 1)]; // in-bin clamp
        process8(ga, gb, 4 * wid + 16 * k, 4 * wid + 16 * (k + 1));
    }

    // ---- reduce the 4 waves' partials in LDS (lane-consecutive, conflict-free) ----
    __shared__ float part[NW * THREADS];    // 4 KB
    part[wid * THREADS + 0 * 64 + lane] = a0;
    part[wid * THREADS + 1 * 64 + lane] = a1;
    part[wid * THREADS + 2 * 64 + lane] = a2;
    part[wid * THREADS + 3 * 64 + lane] = a3;
    __syncthreads();

    // thread tid owns pixel p=tid: q = tid>>6, lane' = tid&63
    const int q     = tid >> 6;
    const int lane2 = tid & 63;
    const int row   = r0 + ((lane2 >> 4) << 2) + q;
    const int cst   = c0 + (lane2 & 15);
    const float v = part[0 * THREADS + tid] + part[1 * THREADS + tid] +
                    part[2 * THREADS + tid] + part[3 * THREADS + tid];
    if (row < S && cst < S) {
        out[(size_t)b * (S * S) + row * S + cst] = v;
    }
}

extern "C" void kernel_launch(void* const* d_in, const int* in_sizes, int n_in,
                              void* d_out, int out_size, void* d_ws, size_t ws_size,
                              hipStream_t stream)
{
    const float* img = (const float*)d_in[0];   // [B, E, P, P] fp32
    const int*   xyz = (const int*)d_in[1];     // [B, E, 3] int32
    float*       out = (float*)d_out;           // [B, 1, S, S] fp32

    unsigned* entries = (unsigned*)d_ws;         // NBINS * CAP words (~5.5 MB)

    imgs4dto3d_bin_kernel<<<B, E, 0, stream>>>(xyz, entries);

    imgs4dto3d_gather_kernel<<<NBINS, THREADS, 0, stream>>>(img, entries, out);
}